// Round 7
// baseline (475.710 us; speedup 1.0000x reference)
//
#include <hip/hip_runtime.h>

// ---------------------------------------------------------------------------
// SNN Perceptron Equalizer (LIF recurrent net), MI355X
//
//  * ff = xt@W_in^T  ->  <=3 precomputed rows P[t][seg][sym][h] (fp64-built).
//  * One WAVE per batch element; lane l holds h=4l..4l+3 (f32x4 state).
//    16 waves / 1024-thread block, 1 block/CU.
//  * Recurrence z@W_rec^T: rows 0..123 of pre-transposed W_rec live in LDS
//    (124KB fp32, staged once; LDS pipe is separate from the L1 port that
//    the gather otherwise saturates); rows 124..255 from L2. Mask split is
//    exact at lane 31 (4*31+0=124).
//  * Schedule per step t: spike/ballot(z_t) -> consume gathers(z_{t-1})
//    (issued LATE last iter => ~0.7 iter in flight) -> i_t -> issue P(t+1)
//    -> issue exact-c gathers(z_t) into 2 named slots per mask x {LDS,GLB}
//    (64 VGPRs in flight); overflow (rare) summed synchronously into rsync.
//  * Epilogue LDS-free: W_out^T table + 64-lane butterfly reduction.
//  * z_sum[b,:] = 32*b_out + sum_h cnt[b,h]*W_out[:,h]; rate = spikes/2^25.
// ---------------------------------------------------------------------------

typedef float f32x4 __attribute__((ext_vector_type(4)));

#define T_STEPS 32
#define FDIM    41
#define ODIM    16
#define BDIM    4096
#define MF      164

#define P_FLOATS   (32 * 3 * 16 * 256)
#define WT_ROWS    257                  // row 256 = zeros
#define WT_FLOATS  (WT_ROWS * 256)
#define WOT_FLOATS (256 * 16)
#define LROWS      124                  // WT rows resident in LDS

#define HAS3(T) ((((T) * MF) & 127) > 92)

// ---------------------------------------------------------------------------
// K1: build P (fp64 accum), transpose W_rec (+zero row), W_out^T, counter=0.
// blocks 0..383: P; 384..640: W_rec^T; 641: W_out^T.
// ---------------------------------------------------------------------------
__global__ __launch_bounds__(256) void k_prep(const float* __restrict__ emb,
                                              const float* __restrict__ W_in,
                                              const float* __restrict__ W_rec,
                                              const float* __restrict__ W_out,
                                              float* __restrict__ P,
                                              float* __restrict__ WT,
                                              float* __restrict__ WOT,
                                              int* __restrict__ counter)
{
    const int bid = blockIdx.x;
    const int tid = threadIdx.x;

    if (bid < 384) {
        const int g  = bid & 3;
        const int ts = bid >> 2;
        const int t  = ts / 3;
        const int si = ts % 3;
        const int k0   = t * MF;
        const int f    = (k0 >> 7) + si;
        const int base = f << 7;
        const int c0   = max(k0, base) - base;
        const int c1   = min(k0 + MF, base + 128) - base;
        const int len  = c1 - c0;

        if (len <= 0) {
            #pragma unroll
            for (int s = 0; s < 4; ++s)
                P[((t * 3 + si) * 16 + 4 * g + s) * 256 + tid] = 0.0f;
            return;
        }

        __shared__ float emb_lds[4][128];
        for (int idx = tid; idx < 4 * 128; idx += 256) {
            const int s = idx >> 7, u = idx & 127;
            if (u < len) emb_lds[s][u] = emb[((4 * g + s) << 7) + c0 + u];
        }
        __syncthreads();

        const int j0 = base + c0 - k0;
        double a0 = 0.0, a1 = 0.0, a2 = 0.0, a3 = 0.0;
        for (int u = 0; u < len; ++u) {
            const double w = (double)W_in[tid * MF + j0 + u];
            a0 += w * (double)emb_lds[0][u];
            a1 += w * (double)emb_lds[1][u];
            a2 += w * (double)emb_lds[2][u];
            a3 += w * (double)emb_lds[3][u];
        }
        P[((t * 3 + si) * 16 + 4 * g + 0) * 256 + tid] = (float)a0;
        P[((t * 3 + si) * 16 + 4 * g + 1) * 256 + tid] = (float)a1;
        P[((t * 3 + si) * 16 + 4 * g + 2) * 256 + tid] = (float)a2;
        P[((t * 3 + si) * 16 + 4 * g + 3) * 256 + tid] = (float)a3;
    } else if (bid < 641) {
        const int h = bid - 384;                // 0..256
        if (h < 256) {
            WT[h * 256 + tid] = W_rec[tid * 256 + h];
        } else {
            WT[256 * 256 + tid] = 0.0f;
            if (tid == 0) *counter = 0;
        }
    } else {
        // W_out^T: WOT[h][o] = W_out[o][h]
        #pragma unroll
        for (int o = 0; o < ODIM; ++o)
            WOT[tid * ODIM + o] = W_out[o * 256 + tid];
    }
}

// ---------------------------------------------------------------------------
// K2: main LIF scan. 256 blocks x 1024 threads (16 waves, wave = batch elem).
// ---------------------------------------------------------------------------
__global__ __launch_bounds__(1024) void k_main(const int* __restrict__ x,
                                               const float* __restrict__ P,
                                               const float* __restrict__ WT,
                                               const float* __restrict__ WOT,
                                               const float* __restrict__ b_out,
                                               float* __restrict__ out,
                                               int* __restrict__ counter)
{
#pragma clang fp contract(off)
    __shared__ f32x4 WTl[LROWS * 64];      // 124 KB: WT rows 0..123
    __shared__ int   red[16];

    const int tid  = threadIdx.x;
    const int lane = tid & 63;
    const int wv   = __builtin_amdgcn_readfirstlane(tid >> 6);
    const int b    = blockIdx.x * 16 + wv;

    const f32x4* __restrict__ P4  = (const f32x4*)P;
    const f32x4* __restrict__ WT4 = (const f32x4*)WT;

    // stage WT rows 0..123 into LDS (layout identical: row*64 + lane)
    for (int i = tid; i < LROWS * 64; i += 1024) WTl[i] = WT4[i];
    __syncthreads();

    const int xv = (lane < FDIM) ? x[b * FDIM + lane] : 0;

    const f32x4 zero4 = {0.f, 0.f, 0.f, 0.f};
    f32x4 vm = zero4, cur = zero4, rsync = zero4;
    f32x4 gL00 = zero4, gL01 = zero4, gL10 = zero4, gL11 = zero4,
          gL20 = zero4, gL21 = zero4, gL30 = zero4, gL31 = zero4;
    f32x4 gG00 = zero4, gG01 = zero4, gG10 = zero4, gG11 = zero4,
          gG20 = zero4, gG21 = zero4, gG30 = zero4, gG31 = zero4;
    f32x4 pP0 = zero4, pP1 = zero4, pP2 = zero4;
    int cL0 = 0, cL1 = 0, cL2 = 0, cL3 = 0;
    int cG0 = 0, cG1 = 0, cG2 = 0, cG3 = 0;
    int n0 = 0, n1 = 0, n2 = 0, n3 = 0;

    // prologue: ff rows for t=0 (no seg2 at t=0)
    {
        const int s0 = __builtin_amdgcn_readlane(xv, 0);
        const int s1 = __builtin_amdgcn_readlane(xv, 1);
        pP0 = P4[(0 * 16 + s0) * 64 + lane];
        pP1 = P4[(1 * 16 + s1) * 64 + lane];
    }

    // exact-c gather issue for one mask: 2 LDS slots + 2 GLB slots + sync
    // overflow into rsync. Split at lane 31: rows<124 in LDS.
    #define GATHER(K, M, GL0, GL1, GG0, GG1, CL, CG)                          \
    {                                                                         \
        unsigned long long mL = (M) & 0x7FFFFFFFULL;                          \
        unsigned long long mG = (M) >> 31;                                    \
        CL = __popcll(mL);  CG = __popcll(mG);                                \
        if (mL) {                                                             \
            int r = 4 * (int)__builtin_ctzll(mL) + (K); mL &= mL - 1;         \
            GL0 = WTl[r * 64 + lane];                                         \
            if (mL) {                                                         \
                r = 4 * (int)__builtin_ctzll(mL) + (K); mL &= mL - 1;         \
                GL1 = WTl[r * 64 + lane];                                     \
                while (mL) {                                                  \
                    r = 4 * (int)__builtin_ctzll(mL) + (K); mL &= mL - 1;     \
                    rsync += WTl[r * 64 + lane];                              \
                }                                                             \
            }                                                                 \
        }                                                                     \
        if (mG) {                                                             \
            int r = 4 * (31 + (int)__builtin_ctzll(mG)) + (K); mG &= mG - 1;  \
            GG0 = WT4[r * 64 + lane];                                         \
            if (mG) {                                                         \
                r = 4 * (31 + (int)__builtin_ctzll(mG)) + (K); mG &= mG - 1;  \
                GG1 = WT4[r * 64 + lane];                                     \
                while (mG) {                                                  \
                    r = 4 * (31 + (int)__builtin_ctzll(mG)) + (K); mG &= mG-1;\
                    rsync += WT4[r * 64 + lane];                              \
                }                                                             \
            }                                                                 \
        }                                                                     \
    }

    for (int t = 0; t < T_STEPS; ++t) {
        // 1. membrane decay + spike decision
        const f32x4 vdec = vm + 0.1f * (cur - vm);
        const f32x4 idec = cur * 0.8f;
        const bool z0 = vdec.x > 1.0f, z1 = vdec.y > 1.0f,
                   z2 = vdec.z > 1.0f, z3 = vdec.w > 1.0f;
        const unsigned long long m0 = __ballot(z0), m1 = __ballot(z1),
                                 m2 = __ballot(z2), m3 = __ballot(z3);
        vm.x = z0 ? 0.0f : vdec.x;  vm.y = z1 ? 0.0f : vdec.y;
        vm.z = z2 ? 0.0f : vdec.z;  vm.w = z3 ? 0.0f : vdec.w;
        n0 += z0; n1 += z1; n2 += z2; n3 += z3;

        // 2. consume gathers of z_{t-1} (issued late last iter)
        f32x4 rec = rsync;
        if (cL0 > 0) rec += gL00;  if (cL0 > 1) rec += gL01;
        if (cL1 > 0) rec += gL10;  if (cL1 > 1) rec += gL11;
        if (cL2 > 0) rec += gL20;  if (cL2 > 1) rec += gL21;
        if (cL3 > 0) rec += gL30;  if (cL3 > 1) rec += gL31;
        if (cG0 > 0) rec += gG00;  if (cG0 > 1) rec += gG01;
        if (cG1 > 0) rec += gG10;  if (cG1 > 1) rec += gG11;
        if (cG2 > 0) rec += gG20;  if (cG2 > 1) rec += gG21;
        if (cG3 > 0) rec += gG30;  if (cG3 > 1) rec += gG31;

        // 3. feedforward + new current  (i_t uses z_{t-1} recurrence ✓)
        f32x4 ff = pP0 + pP1;
        if (((t * MF) & 127) > 92) ff += pP2;
        cur = (idec + ff) + rec;

        // 4. issue P rows for t+1
        if (t + 1 < T_STEPS) {
            const int tn = t + 1;
            const int f0 = (tn * MF) >> 7;
            const int s0 = __builtin_amdgcn_readlane(xv, f0);
            const int s1 = __builtin_amdgcn_readlane(xv, f0 + 1);
            pP0 = P4[((tn * 3 + 0) * 16 + s0) * 64 + lane];
            pP1 = P4[((tn * 3 + 1) * 16 + s1) * 64 + lane];
            if (((tn * MF) & 127) > 92) {
                const int s2 = __builtin_amdgcn_readlane(xv, f0 + 2);
                pP2 = P4[((tn * 3 + 2) * 16 + s2) * 64 + lane];
            }
        }

        // 5. issue gathers for z_t (consumed next iter)
        rsync = zero4;
        GATHER(0, m0, gL00, gL01, gG00, gG01, cL0, cG0)
        GATHER(1, m1, gL10, gL11, gG10, gG11, cL1, cG1)
        GATHER(2, m2, gL20, gL21, gG20, gG21, cL2, cG2)
        GATHER(3, m3, gL30, gL31, gG30, gG31, cL3, cG3)
    }
    #undef GATHER

    // --- epilogue: z_sum[b,o] = 32*b_out[o] + sum_h cnt[h]*W_out[o,h] ---
    // counts live in n0..n3 for h = 4*lane+k; use W_out^T + lane butterfly.
    {
        const f32x4* __restrict__ WOT4 = (const f32x4*)WOT; // [256][4] of f32x4
        const float fn0 = (float)n0, fn1 = (float)n1,
                    fn2 = (float)n2, fn3 = (float)n3;
        const int r0 = 4 * lane * 4;   // f32x4 index of row 4*lane, quarter 0
        f32x4 a0 = fn0 * WOT4[r0 + 0]  + fn1 * WOT4[r0 + 4]
                 + fn2 * WOT4[r0 + 8]  + fn3 * WOT4[r0 + 12];
        f32x4 a1 = fn0 * WOT4[r0 + 1]  + fn1 * WOT4[r0 + 5]
                 + fn2 * WOT4[r0 + 9]  + fn3 * WOT4[r0 + 13];
        f32x4 a2 = fn0 * WOT4[r0 + 2]  + fn1 * WOT4[r0 + 6]
                 + fn2 * WOT4[r0 + 10] + fn3 * WOT4[r0 + 14];
        f32x4 a3 = fn0 * WOT4[r0 + 3]  + fn1 * WOT4[r0 + 7]
                 + fn2 * WOT4[r0 + 11] + fn3 * WOT4[r0 + 15];

        #pragma unroll
        for (int off = 1; off < 64; off <<= 1) {
            f32x4 t0, t1, t2, t3;
            t0.x = __shfl_xor(a0.x, off, 64); t0.y = __shfl_xor(a0.y, off, 64);
            t0.z = __shfl_xor(a0.z, off, 64); t0.w = __shfl_xor(a0.w, off, 64);
            t1.x = __shfl_xor(a1.x, off, 64); t1.y = __shfl_xor(a1.y, off, 64);
            t1.z = __shfl_xor(a1.z, off, 64); t1.w = __shfl_xor(a1.w, off, 64);
            t2.x = __shfl_xor(a2.x, off, 64); t2.y = __shfl_xor(a2.y, off, 64);
            t2.z = __shfl_xor(a2.z, off, 64); t2.w = __shfl_xor(a2.w, off, 64);
            t3.x = __shfl_xor(a3.x, off, 64); t3.y = __shfl_xor(a3.y, off, 64);
            t3.z = __shfl_xor(a3.z, off, 64); t3.w = __shfl_xor(a3.w, off, 64);
            a0 += t0; a1 += t1; a2 += t2; a3 += t3;
        }

        int spk = n0 + n1 + n2 + n3;
        #pragma unroll
        for (int off = 1; off < 64; off <<= 1)
            spk += __shfl_xor(spk, off, 64);
        if (lane == 0) red[wv] = spk;

        if (lane < 4) {
            const f32x4 acc = (lane == 0) ? a0 : (lane == 1) ? a1
                              : (lane == 2) ? a2 : a3;
            const f32x4 bo = ((const f32x4*)b_out)[lane];
            ((f32x4*)out)[b * 4 + lane] = 32.0f * bo + acc;
        }
    }

    __syncthreads();
    if (tid == 0) {
        int s = 0;
        #pragma unroll
        for (int i = 0; i < 16; ++i) s += red[i];
        atomicAdd(counter, s);
    }
}

// ---------------------------------------------------------------------------
// K3: spikerate = count / 2^25 (exact in fp32 since count < 2^24)
// ---------------------------------------------------------------------------
__global__ void k_fin(const int* __restrict__ counter, float* __restrict__ out)
{
    out[BDIM * ODIM] = (float)(*counter) * (1.0f / 33554432.0f);
}

// ---------------------------------------------------------------------------
extern "C" void kernel_launch(void* const* d_in, const int* in_sizes, int n_in,
                              void* d_out, int out_size, void* d_ws, size_t ws_size,
                              hipStream_t stream)
{
    const int*   x     = (const int*)  d_in[0];
    const float* emb   = (const float*)d_in[1];
    const float* W_in  = (const float*)d_in[2];
    const float* W_rec = (const float*)d_in[3];
    const float* W_out = (const float*)d_in[4];
    const float* b_out = (const float*)d_in[5];
    float* out = (float*)d_out;

    float* P       = (float*)d_ws;
    float* WT      = P + P_FLOATS;
    float* WOT     = WT + WT_FLOATS;
    int*   counter = (int*)(WOT + WOT_FLOATS);

    k_prep<<<642, 256, 0, stream>>>(emb, W_in, W_rec, W_out, P, WT, WOT, counter);
    k_main<<<BDIM / 16, 1024, 0, stream>>>(x, P, WT, WOT, b_out, out, counter);
    k_fin<<<1, 1, 0, stream>>>(counter, out);
}

// Round 8
// 109.420 us; speedup vs baseline: 4.3476x; 4.3476x over previous
//
#include <hip/hip_runtime.h>

// ---------------------------------------------------------------------------
// SNN Perceptron Equalizer (LIF recurrent net), MI355X
//
//  * ff = xt@W_in^T  ->  <=3 precomputed rows P[t][seg][sym][h] (fp64-built).
//  * One WAVE per batch element; lane l holds h=4l..4l+3 (f32x4 state).
//    8 waves / 512-thread block, 1 block/CU (LDS-limited).
//    __launch_bounds__(512,2) -> 256-VGPR cap: the ~140-VGPR body fits
//    WITHOUT spilling (round 7 failed purely because 1024 threads forced a
//    64-VGPR cap -> 1.8 GB of scratch traffic).
//  * Recurrence z@W_rec^T: rows 0..123 of pre-transposed W_rec in LDS
//    (124 KB fp32; LDS pipe ~307 GB/s/CU runs parallel to the ~134 GB/s/CU
//    L2 share the gather otherwise saturates); rows 124..255 from L2.
//    Mask split exact at lane 31 (4*31=124).
//  * Per step t: spike/ballot(z_t) -> consume gathers(z_{t-1}) issued late
//    last iter -> i_t -> issue P(t+1) -> issue exact-c gathers(z_t) into
//    2 named slots per mask x {LDS,GLB}; rare overflow summed synchronously.
//  * Epilogue LDS-free: W_out^T + 64-lane butterfly.
//  * z_sum[b,:] = 32*b_out + sum_h cnt[b,h]*W_out[:,h]; rate = spikes/2^25.
// ---------------------------------------------------------------------------

typedef float f32x4 __attribute__((ext_vector_type(4)));

#define T_STEPS 32
#define FDIM    41
#define ODIM    16
#define BDIM    4096
#define MF      164

#define P_FLOATS   (32 * 3 * 16 * 256)
#define WT_ROWS    257                  // row 256 = zeros
#define WT_FLOATS  (WT_ROWS * 256)
#define WOT_FLOATS (256 * 16)
#define LROWS      124                  // WT rows resident in LDS
#define NWAVES     8                    // waves per block

#define HAS3(T) ((((T) * MF) & 127) > 92)

// ---------------------------------------------------------------------------
// K1: build P (fp64 accum), transpose W_rec (+zero row), W_out^T, counter=0.
// blocks 0..383: P; 384..640: W_rec^T; 641: W_out^T.
// ---------------------------------------------------------------------------
__global__ __launch_bounds__(256) void k_prep(const float* __restrict__ emb,
                                              const float* __restrict__ W_in,
                                              const float* __restrict__ W_rec,
                                              const float* __restrict__ W_out,
                                              float* __restrict__ P,
                                              float* __restrict__ WT,
                                              float* __restrict__ WOT,
                                              int* __restrict__ counter)
{
    const int bid = blockIdx.x;
    const int tid = threadIdx.x;

    if (bid < 384) {
        const int g  = bid & 3;
        const int ts = bid >> 2;
        const int t  = ts / 3;
        const int si = ts % 3;
        const int k0   = t * MF;
        const int f    = (k0 >> 7) + si;
        const int base = f << 7;
        const int c0   = max(k0, base) - base;
        const int c1   = min(k0 + MF, base + 128) - base;
        const int len  = c1 - c0;

        if (len <= 0) {
            #pragma unroll
            for (int s = 0; s < 4; ++s)
                P[((t * 3 + si) * 16 + 4 * g + s) * 256 + tid] = 0.0f;
            return;
        }

        __shared__ float emb_lds[4][128];
        for (int idx = tid; idx < 4 * 128; idx += 256) {
            const int s = idx >> 7, u = idx & 127;
            if (u < len) emb_lds[s][u] = emb[((4 * g + s) << 7) + c0 + u];
        }
        __syncthreads();

        const int j0 = base + c0 - k0;
        double a0 = 0.0, a1 = 0.0, a2 = 0.0, a3 = 0.0;
        for (int u = 0; u < len; ++u) {
            const double w = (double)W_in[tid * MF + j0 + u];
            a0 += w * (double)emb_lds[0][u];
            a1 += w * (double)emb_lds[1][u];
            a2 += w * (double)emb_lds[2][u];
            a3 += w * (double)emb_lds[3][u];
        }
        P[((t * 3 + si) * 16 + 4 * g + 0) * 256 + tid] = (float)a0;
        P[((t * 3 + si) * 16 + 4 * g + 1) * 256 + tid] = (float)a1;
        P[((t * 3 + si) * 16 + 4 * g + 2) * 256 + tid] = (float)a2;
        P[((t * 3 + si) * 16 + 4 * g + 3) * 256 + tid] = (float)a3;
    } else if (bid < 641) {
        const int h = bid - 384;                // 0..256
        if (h < 256) {
            WT[h * 256 + tid] = W_rec[tid * 256 + h];
        } else {
            WT[256 * 256 + tid] = 0.0f;
            if (tid == 0) *counter = 0;
        }
    } else {
        // W_out^T: WOT[h][o] = W_out[o][h]
        #pragma unroll
        for (int o = 0; o < ODIM; ++o)
            WOT[tid * ODIM + o] = W_out[o * 256 + tid];
    }
}

// ---------------------------------------------------------------------------
// K2: main LIF scan. 512 blocks x 512 threads (8 waves, wave = batch elem).
// ---------------------------------------------------------------------------
__global__ __launch_bounds__(512, 2) void k_main(const int* __restrict__ x,
                                                 const float* __restrict__ P,
                                                 const float* __restrict__ WT,
                                                 const float* __restrict__ WOT,
                                                 const float* __restrict__ b_out,
                                                 float* __restrict__ out,
                                                 int* __restrict__ counter)
{
#pragma clang fp contract(off)
    __shared__ f32x4 WTl[LROWS * 64];      // 124 KB: WT rows 0..123
    __shared__ int   red[NWAVES];

    const int tid  = threadIdx.x;
    const int lane = tid & 63;
    const int wv   = __builtin_amdgcn_readfirstlane(tid >> 6);
    const int b    = blockIdx.x * NWAVES + wv;

    const f32x4* __restrict__ P4  = (const f32x4*)P;
    const f32x4* __restrict__ WT4 = (const f32x4*)WT;

    // stage WT rows 0..123 into LDS (layout identical: row*64 + lane)
    for (int i = tid; i < LROWS * 64; i += 512) WTl[i] = WT4[i];
    __syncthreads();

    const int xv = (lane < FDIM) ? x[b * FDIM + lane] : 0;

    const f32x4 zero4 = {0.f, 0.f, 0.f, 0.f};
    f32x4 vm = zero4, cur = zero4, rsync = zero4;
    f32x4 gL00 = zero4, gL01 = zero4, gL10 = zero4, gL11 = zero4,
          gL20 = zero4, gL21 = zero4, gL30 = zero4, gL31 = zero4;
    f32x4 gG00 = zero4, gG01 = zero4, gG10 = zero4, gG11 = zero4,
          gG20 = zero4, gG21 = zero4, gG30 = zero4, gG31 = zero4;
    f32x4 pP0 = zero4, pP1 = zero4, pP2 = zero4;
    int cL0 = 0, cL1 = 0, cL2 = 0, cL3 = 0;
    int cG0 = 0, cG1 = 0, cG2 = 0, cG3 = 0;
    int n0 = 0, n1 = 0, n2 = 0, n3 = 0;

    // prologue: ff rows for t=0 (no seg2 at t=0)
    {
        const int s0 = __builtin_amdgcn_readlane(xv, 0);
        const int s1 = __builtin_amdgcn_readlane(xv, 1);
        pP0 = P4[(0 * 16 + s0) * 64 + lane];
        pP1 = P4[(1 * 16 + s1) * 64 + lane];
    }

    // exact-c gather issue for one mask: 2 LDS slots + 2 GLB slots; overflow
    // into rsync synchronously. Split at lane 31: rows<124 in LDS.
    #define GATHER(K, M, GL0, GL1, GG0, GG1, CL, CG)                          \
    {                                                                         \
        unsigned long long mL = (M) & 0x7FFFFFFFULL;                          \
        unsigned long long mG = (M) >> 31;                                    \
        CL = __popcll(mL);  CG = __popcll(mG);                                \
        if (mL) {                                                             \
            int r = 4 * (int)__builtin_ctzll(mL) + (K); mL &= mL - 1;         \
            GL0 = WTl[r * 64 + lane];                                         \
            if (mL) {                                                         \
                r = 4 * (int)__builtin_ctzll(mL) + (K); mL &= mL - 1;         \
                GL1 = WTl[r * 64 + lane];                                     \
                while (mL) {                                                  \
                    r = 4 * (int)__builtin_ctzll(mL) + (K); mL &= mL - 1;     \
                    rsync += WTl[r * 64 + lane];                              \
                }                                                             \
            }                                                                 \
        }                                                                     \
        if (mG) {                                                             \
            int r = 4 * (31 + (int)__builtin_ctzll(mG)) + (K); mG &= mG - 1;  \
            GG0 = WT4[r * 64 + lane];                                         \
            if (mG) {                                                         \
                r = 4 * (31 + (int)__builtin_ctzll(mG)) + (K); mG &= mG - 1;  \
                GG1 = WT4[r * 64 + lane];                                     \
                while (mG) {                                                  \
                    r = 4 * (31 + (int)__builtin_ctzll(mG)) + (K); mG &= mG-1;\
                    rsync += WT4[r * 64 + lane];                              \
                }                                                             \
            }                                                                 \
        }                                                                     \
    }

    for (int t = 0; t < T_STEPS; ++t) {
        // 1. membrane decay + spike decision
        const f32x4 vdec = vm + 0.1f * (cur - vm);
        const f32x4 idec = cur * 0.8f;
        const bool z0 = vdec.x > 1.0f, z1 = vdec.y > 1.0f,
                   z2 = vdec.z > 1.0f, z3 = vdec.w > 1.0f;
        const unsigned long long m0 = __ballot(z0), m1 = __ballot(z1),
                                 m2 = __ballot(z2), m3 = __ballot(z3);
        vm.x = z0 ? 0.0f : vdec.x;  vm.y = z1 ? 0.0f : vdec.y;
        vm.z = z2 ? 0.0f : vdec.z;  vm.w = z3 ? 0.0f : vdec.w;
        n0 += z0; n1 += z1; n2 += z2; n3 += z3;

        // 2. consume gathers of z_{t-1} (issued late last iter)
        f32x4 rec = rsync;
        if (cL0 > 0) rec += gL00;  if (cL0 > 1) rec += gL01;
        if (cL1 > 0) rec += gL10;  if (cL1 > 1) rec += gL11;
        if (cL2 > 0) rec += gL20;  if (cL2 > 1) rec += gL21;
        if (cL3 > 0) rec += gL30;  if (cL3 > 1) rec += gL31;
        if (cG0 > 0) rec += gG00;  if (cG0 > 1) rec += gG01;
        if (cG1 > 0) rec += gG10;  if (cG1 > 1) rec += gG11;
        if (cG2 > 0) rec += gG20;  if (cG2 > 1) rec += gG21;
        if (cG3 > 0) rec += gG30;  if (cG3 > 1) rec += gG31;

        // 3. feedforward + new current  (i_t uses z_{t-1} recurrence)
        f32x4 ff = pP0 + pP1;
        if (((t * MF) & 127) > 92) ff += pP2;
        cur = (idec + ff) + rec;

        // 4. issue P rows for t+1
        if (t + 1 < T_STEPS) {
            const int tn = t + 1;
            const int f0 = (tn * MF) >> 7;
            const int s0 = __builtin_amdgcn_readlane(xv, f0);
            const int s1 = __builtin_amdgcn_readlane(xv, f0 + 1);
            pP0 = P4[((tn * 3 + 0) * 16 + s0) * 64 + lane];
            pP1 = P4[((tn * 3 + 1) * 16 + s1) * 64 + lane];
            if (((tn * MF) & 127) > 92) {
                const int s2 = __builtin_amdgcn_readlane(xv, f0 + 2);
                pP2 = P4[((tn * 3 + 2) * 16 + s2) * 64 + lane];
            }

            // 5. issue gathers for z_t (consumed next iter)
            rsync = zero4;
            GATHER(0, m0, gL00, gL01, gG00, gG01, cL0, cG0)
            GATHER(1, m1, gL10, gL11, gG10, gG11, cL1, cG1)
            GATHER(2, m2, gL20, gL21, gG20, gG21, cL2, cG2)
            GATHER(3, m3, gL30, gL31, gG30, gG31, cL3, cG3)
        }
    }
    #undef GATHER

    // --- epilogue: z_sum[b,o] = 32*b_out[o] + sum_h cnt[h]*W_out[o,h] ---
    // counts live in n0..n3 for h = 4*lane+k; W_out^T + 64-lane butterfly.
    {
        const f32x4* __restrict__ WOT4 = (const f32x4*)WOT; // [256][4] f32x4
        const float fn0 = (float)n0, fn1 = (float)n1,
                    fn2 = (float)n2, fn3 = (float)n3;
        const int r0 = 4 * lane * 4;   // f32x4 index of row 4*lane, quarter 0
        f32x4 a0 = fn0 * WOT4[r0 + 0]  + fn1 * WOT4[r0 + 4]
                 + fn2 * WOT4[r0 + 8]  + fn3 * WOT4[r0 + 12];
        f32x4 a1 = fn0 * WOT4[r0 + 1]  + fn1 * WOT4[r0 + 5]
                 + fn2 * WOT4[r0 + 9]  + fn3 * WOT4[r0 + 13];
        f32x4 a2 = fn0 * WOT4[r0 + 2]  + fn1 * WOT4[r0 + 6]
                 + fn2 * WOT4[r0 + 10] + fn3 * WOT4[r0 + 14];
        f32x4 a3 = fn0 * WOT4[r0 + 3]  + fn1 * WOT4[r0 + 7]
                 + fn2 * WOT4[r0 + 11] + fn3 * WOT4[r0 + 15];

        #pragma unroll
        for (int off = 1; off < 64; off <<= 1) {
            f32x4 t0, t1, t2, t3;
            t0.x = __shfl_xor(a0.x, off, 64); t0.y = __shfl_xor(a0.y, off, 64);
            t0.z = __shfl_xor(a0.z, off, 64); t0.w = __shfl_xor(a0.w, off, 64);
            t1.x = __shfl_xor(a1.x, off, 64); t1.y = __shfl_xor(a1.y, off, 64);
            t1.z = __shfl_xor(a1.z, off, 64); t1.w = __shfl_xor(a1.w, off, 64);
            t2.x = __shfl_xor(a2.x, off, 64); t2.y = __shfl_xor(a2.y, off, 64);
            t2.z = __shfl_xor(a2.z, off, 64); t2.w = __shfl_xor(a2.w, off, 64);
            t3.x = __shfl_xor(a3.x, off, 64); t3.y = __shfl_xor(a3.y, off, 64);
            t3.z = __shfl_xor(a3.z, off, 64); t3.w = __shfl_xor(a3.w, off, 64);
            a0 += t0; a1 += t1; a2 += t2; a3 += t3;
        }

        int spk = n0 + n1 + n2 + n3;
        #pragma unroll
        for (int off = 1; off < 64; off <<= 1)
            spk += __shfl_xor(spk, off, 64);
        if (lane == 0) red[wv] = spk;

        if (lane < 4) {
            const f32x4 acc = (lane == 0) ? a0 : (lane == 1) ? a1
                              : (lane == 2) ? a2 : a3;
            const f32x4 bo = ((const f32x4*)b_out)[lane];
            ((f32x4*)out)[b * 4 + lane] = 32.0f * bo + acc;
        }
    }

    __syncthreads();
    if (tid == 0) {
        int s = 0;
        #pragma unroll
        for (int i = 0; i < NWAVES; ++i) s += red[i];
        atomicAdd(counter, s);
    }
}

// ---------------------------------------------------------------------------
// K3: spikerate = count / 2^25 (exact in fp32 since count < 2^24)
// ---------------------------------------------------------------------------
__global__ void k_fin(const int* __restrict__ counter, float* __restrict__ out)
{
    out[BDIM * ODIM] = (float)(*counter) * (1.0f / 33554432.0f);
}

// ---------------------------------------------------------------------------
extern "C" void kernel_launch(void* const* d_in, const int* in_sizes, int n_in,
                              void* d_out, int out_size, void* d_ws, size_t ws_size,
                              hipStream_t stream)
{
    const int*   x     = (const int*)  d_in[0];
    const float* emb   = (const float*)d_in[1];
    const float* W_in  = (const float*)d_in[2];
    const float* W_rec = (const float*)d_in[3];
    const float* W_out = (const float*)d_in[4];
    const float* b_out = (const float*)d_in[5];
    float* out = (float*)d_out;

    float* P       = (float*)d_ws;
    float* WT      = P + P_FLOATS;
    float* WOT     = WT + WT_FLOATS;
    int*   counter = (int*)(WOT + WOT_FLOATS);

    k_prep<<<642, 256, 0, stream>>>(emb, W_in, W_rec, W_out, P, WT, WOT, counter);
    k_main<<<BDIM / NWAVES, 512, 0, stream>>>(x, P, WT, WOT, b_out, out, counter);
    k_fin<<<1, 1, 0, stream>>>(counter, out);
}

// Round 9
// 67.607 us; speedup vs baseline: 7.0364x; 1.6185x over previous
//
#include <hip/hip_runtime.h>

// ---------------------------------------------------------------------------
// SNN Perceptron Equalizer (LIF recurrent net), MI355X
//
//  * ff = xt@W_in^T  ->  <=3 precomputed rows P[t][seg][sym][h] (fp64-built).
//  * One WAVE per batch element; lane l holds h=4l..4l+3 (f32x4 state).
//    ONE 1024-thread block (16 waves) per CU -> 16 waves/CU of TLP.
//    __launch_bounds__(1024,4) -> 128-VGPR cap, no spill (body ~100).
//  * Recurrence z@W_rec^T is L2-BW-bound (c ~= 12 spikes/wave-step x 1KB
//    rows). Split: rows 0..143 (56%) in LDS (145KB; separate 128B/clk pipe),
//    rows 144..255 from L2. Gather is BATCHED: peel up to 4 global + 4 LDS
//    ids per iteration (SALU), issue 8 independent loads, wait once, sum.
//    Dummy slots target zero rows (L1/LDS-resident -> no L2 bytes).
//  * z_sum[b,:] = 32*b_out + sum_h cnt[b,h]*W_out[:,h]; rate = spikes/2^25.
// ---------------------------------------------------------------------------

typedef float f32x4 __attribute__((ext_vector_type(4)));

#define T_STEPS 32
#define FDIM    41
#define ODIM    16
#define BDIM    4096
#define MF      164

#define P_FLOATS   (32 * 3 * 16 * 256)
#define WT_ROWS    257                  // row 256 = zeros (global dummy)
#define WT_FLOATS  (WT_ROWS * 256)
#define WOT_FLOATS (256 * 16)

#define LROWS      144                  // WT rows 0..143 in LDS
#define LBITS      36                   // 4*36 = 144: mask split bit
#define NW         16                   // waves per block

// ---------------------------------------------------------------------------
// K1: build P (fp64 accum), transpose W_rec (+zero row), W_out^T, counter=0.
// blocks 0..383: P; 384..640: W_rec^T (+zero row at 640); 641: W_out^T.
// ---------------------------------------------------------------------------
__global__ __launch_bounds__(256) void k_prep(const float* __restrict__ emb,
                                              const float* __restrict__ W_in,
                                              const float* __restrict__ W_rec,
                                              const float* __restrict__ W_out,
                                              float* __restrict__ P,
                                              float* __restrict__ WT,
                                              float* __restrict__ WOT,
                                              int* __restrict__ counter)
{
    const int bid = blockIdx.x;
    const int tid = threadIdx.x;

    if (bid < 384) {
        const int g  = bid & 3;
        const int ts = bid >> 2;
        const int t  = ts / 3;
        const int si = ts % 3;
        const int k0   = t * MF;
        const int f    = (k0 >> 7) + si;
        const int base = f << 7;
        const int c0   = max(k0, base) - base;
        const int c1   = min(k0 + MF, base + 128) - base;
        const int len  = c1 - c0;

        if (len <= 0) {
            #pragma unroll
            for (int s = 0; s < 4; ++s)
                P[((t * 3 + si) * 16 + 4 * g + s) * 256 + tid] = 0.0f;
            return;
        }

        __shared__ float emb_lds[4][128];
        for (int idx = tid; idx < 4 * 128; idx += 256) {
            const int s = idx >> 7, u = idx & 127;
            if (u < len) emb_lds[s][u] = emb[((4 * g + s) << 7) + c0 + u];
        }
        __syncthreads();

        const int j0 = base + c0 - k0;
        double a0 = 0.0, a1 = 0.0, a2 = 0.0, a3 = 0.0;
        for (int u = 0; u < len; ++u) {
            const double w = (double)W_in[tid * MF + j0 + u];
            a0 += w * (double)emb_lds[0][u];
            a1 += w * (double)emb_lds[1][u];
            a2 += w * (double)emb_lds[2][u];
            a3 += w * (double)emb_lds[3][u];
        }
        P[((t * 3 + si) * 16 + 4 * g + 0) * 256 + tid] = (float)a0;
        P[((t * 3 + si) * 16 + 4 * g + 1) * 256 + tid] = (float)a1;
        P[((t * 3 + si) * 16 + 4 * g + 2) * 256 + tid] = (float)a2;
        P[((t * 3 + si) * 16 + 4 * g + 3) * 256 + tid] = (float)a3;
    } else if (bid < 641) {
        const int h = bid - 384;                // 0..256
        if (h < 256) {
            WT[h * 256 + tid] = W_rec[tid * 256 + h];
        } else {
            WT[256 * 256 + tid] = 0.0f;
            if (tid == 0) *counter = 0;
        }
    } else {
        // W_out^T: WOT[h][o] = W_out[o][h]
        #pragma unroll
        for (int o = 0; o < ODIM; ++o)
            WOT[tid * ODIM + o] = W_out[o * 256 + tid];
    }
}

// ---------------------------------------------------------------------------
// K2: main LIF scan. 256 blocks x 1024 threads (16 waves, wave = batch elem).
// ---------------------------------------------------------------------------
__global__ __launch_bounds__(1024, 4) void k_main(const int* __restrict__ x,
                                                  const float* __restrict__ P,
                                                  const float* __restrict__ WT,
                                                  const float* __restrict__ WOT,
                                                  const float* __restrict__ b_out,
                                                  float* __restrict__ out,
                                                  int* __restrict__ counter)
{
#pragma clang fp contract(off)
    __shared__ f32x4 WTl[(LROWS + 1) * 64];   // 145 KB (row LROWS = zeros)
    __shared__ int   red[NW];

    const int tid  = threadIdx.x;
    const int lane = tid & 63;
    const int wv   = __builtin_amdgcn_readfirstlane(tid >> 6);
    const int b    = blockIdx.x * NW + wv;

    const f32x4* __restrict__ P4  = (const f32x4*)P;
    const f32x4* __restrict__ WT4 = (const f32x4*)WT;

    // stage WT rows 0..143 into LDS (layout identical: row*64 + lane)
    const f32x4 zero4 = {0.f, 0.f, 0.f, 0.f};
    for (int i = tid; i < LROWS * 64; i += 1024) WTl[i] = WT4[i];
    if (tid < 64) WTl[LROWS * 64 + tid] = zero4;   // zero dummy row
    __syncthreads();

    const int xv = (lane < FDIM) ? x[b * FDIM + lane] : 0;

    f32x4 vm = zero4, cur = zero4;
    f32x4 pP0 = zero4, pP1 = zero4, pP2 = zero4;
    unsigned long long sm0 = 0, sm1 = 0, sm2 = 0, sm3 = 0;  // z_{t-1} masks
    int n0 = 0, n1 = 0, n2 = 0, n3 = 0;

    // prologue: ff rows for t=0 (t=0 has 2 segments)
    {
        const int s0 = __builtin_amdgcn_readlane(xv, 0);
        const int s1 = __builtin_amdgcn_readlane(xv, 1);
        pP0 = P4[(0 * 16 + s0) * 64 + lane];
        pP1 = P4[(1 * 16 + s1) * 64 + lane];
    }

    #define PEEL_G(dst)                                                        \
        if (mG0)      { dst = 4*(LBITS+(int)__builtin_ctzll(mG0))+0; mG0 &= mG0-1; } \
        else if (mG1) { dst = 4*(LBITS+(int)__builtin_ctzll(mG1))+1; mG1 &= mG1-1; } \
        else if (mG2) { dst = 4*(LBITS+(int)__builtin_ctzll(mG2))+2; mG2 &= mG2-1; } \
        else if (mG3) { dst = 4*(LBITS+(int)__builtin_ctzll(mG3))+3; mG3 &= mG3-1; }

    #define PEEL_L(dst)                                                        \
        if (mL0)      { dst = 4*(int)__builtin_ctzll(mL0)+0; mL0 &= mL0-1; }   \
        else if (mL1) { dst = 4*(int)__builtin_ctzll(mL1)+1; mL1 &= mL1-1; }   \
        else if (mL2) { dst = 4*(int)__builtin_ctzll(mL2)+2; mL2 &= mL2-1; }   \
        else if (mL3) { dst = 4*(int)__builtin_ctzll(mL3)+3; mL3 &= mL3-1; }

    for (int t = 0; t < T_STEPS; ++t) {
        // 1. membrane decay + spike decision (z_t)
        const f32x4 vdec = vm + 0.1f * (cur - vm);
        const f32x4 idec = cur * 0.8f;
        const bool z0 = vdec.x > 1.0f, z1 = vdec.y > 1.0f,
                   z2 = vdec.z > 1.0f, z3 = vdec.w > 1.0f;
        const unsigned long long nm0 = __ballot(z0), nm1 = __ballot(z1),
                                 nm2 = __ballot(z2), nm3 = __ballot(z3);
        vm.x = z0 ? 0.0f : vdec.x;  vm.y = z1 ? 0.0f : vdec.y;
        vm.z = z2 ? 0.0f : vdec.z;  vm.w = z3 ? 0.0f : vdec.w;
        n0 += z0; n1 += z1; n2 += z2; n3 += z3;

        // 2. rec = z_{t-1} @ W_rec^T : batched sparse gather (LDS + L2)
        f32x4 rec = zero4;
        {
            const unsigned long long LO = (1ULL << LBITS) - 1;
            unsigned long long mL0 = sm0 & LO, mG0 = sm0 >> LBITS;
            unsigned long long mL1 = sm1 & LO, mG1 = sm1 >> LBITS;
            unsigned long long mL2 = sm2 & LO, mG2 = sm2 >> LBITS;
            unsigned long long mL3 = sm3 & LO, mG3 = sm3 >> LBITS;
            int cG = __popcll(mG0) + __popcll(mG1) + __popcll(mG2) + __popcll(mG3);
            int cL = __popcll(mL0) + __popcll(mL1) + __popcll(mL2) + __popcll(mL3);
            while (cG > 0 || cL > 0) {
                int u0 = 256, u1 = 256, u2 = 256, u3 = 256;     // global dummies
                PEEL_G(u0) PEEL_G(u1) PEEL_G(u2) PEEL_G(u3)
                int w0 = LROWS, w1 = LROWS, w2 = LROWS, w3 = LROWS; // LDS dummies
                PEEL_L(w0) PEEL_L(w1) PEEL_L(w2) PEEL_L(w3)
                const f32x4 a0 = WT4[u0 * 64 + lane];
                const f32x4 a1 = WT4[u1 * 64 + lane];
                const f32x4 a2 = WT4[u2 * 64 + lane];
                const f32x4 a3 = WT4[u3 * 64 + lane];
                const f32x4 b0 = WTl[w0 * 64 + lane];
                const f32x4 b1 = WTl[w1 * 64 + lane];
                const f32x4 b2 = WTl[w2 * 64 + lane];
                const f32x4 b3 = WTl[w3 * 64 + lane];
                rec += ((a0 + a1) + (a2 + a3)) + ((b0 + b1) + (b2 + b3));
                cG -= 4;  cL -= 4;
            }
        }

        // 3. new current (ff prefetched last step; i_t uses z_{t-1} ✓)
        f32x4 ff = pP0 + pP1;
        if (((t * MF) & 127) > 92) ff += pP2;
        cur = (idec + ff) + rec;

        // 4. issue P rows for t+1 (symbol-only addresses)
        if (t + 1 < T_STEPS) {
            const int tn = t + 1;
            const int f0 = (tn * MF) >> 7;
            const int s0 = __builtin_amdgcn_readlane(xv, f0);
            const int s1 = __builtin_amdgcn_readlane(xv, f0 + 1);
            pP0 = P4[((tn * 3 + 0) * 16 + s0) * 64 + lane];
            pP1 = P4[((tn * 3 + 1) * 16 + s1) * 64 + lane];
            if (((tn * MF) & 127) > 92) {
                const int s2 = __builtin_amdgcn_readlane(xv, f0 + 2);
                pP2 = P4[((tn * 3 + 2) * 16 + s2) * 64 + lane];
            }
        }

        // 5. z_t becomes z_{t-1} for the next step
        sm0 = nm0; sm1 = nm1; sm2 = nm2; sm3 = nm3;
    }
    #undef PEEL_G
    #undef PEEL_L

    // --- epilogue: z_sum[b,o] = 32*b_out[o] + sum_h cnt[h]*W_out[o,h] ---
    // counts live in n0..n3 for h = 4*lane+k; W_out^T + 64-lane butterfly.
    {
        const f32x4* __restrict__ WOT4 = (const f32x4*)WOT; // [256][4] f32x4
        const float fn0 = (float)n0, fn1 = (float)n1,
                    fn2 = (float)n2, fn3 = (float)n3;
        const int r0 = 4 * lane * 4;   // f32x4 index of row 4*lane, quarter 0
        f32x4 a0 = fn0 * WOT4[r0 + 0]  + fn1 * WOT4[r0 + 4]
                 + fn2 * WOT4[r0 + 8]  + fn3 * WOT4[r0 + 12];
        f32x4 a1 = fn0 * WOT4[r0 + 1]  + fn1 * WOT4[r0 + 5]
                 + fn2 * WOT4[r0 + 9]  + fn3 * WOT4[r0 + 13];
        f32x4 a2 = fn0 * WOT4[r0 + 2]  + fn1 * WOT4[r0 + 6]
                 + fn2 * WOT4[r0 + 10] + fn3 * WOT4[r0 + 14];
        f32x4 a3 = fn0 * WOT4[r0 + 3]  + fn1 * WOT4[r0 + 7]
                 + fn2 * WOT4[r0 + 11] + fn3 * WOT4[r0 + 15];

        #pragma unroll
        for (int off = 1; off < 64; off <<= 1) {
            f32x4 t0, t1, t2, t3;
            t0.x = __shfl_xor(a0.x, off, 64); t0.y = __shfl_xor(a0.y, off, 64);
            t0.z = __shfl_xor(a0.z, off, 64); t0.w = __shfl_xor(a0.w, off, 64);
            t1.x = __shfl_xor(a1.x, off, 64); t1.y = __shfl_xor(a1.y, off, 64);
            t1.z = __shfl_xor(a1.z, off, 64); t1.w = __shfl_xor(a1.w, off, 64);
            t2.x = __shfl_xor(a2.x, off, 64); t2.y = __shfl_xor(a2.y, off, 64);
            t2.z = __shfl_xor(a2.z, off, 64); t2.w = __shfl_xor(a2.w, off, 64);
            t3.x = __shfl_xor(a3.x, off, 64); t3.y = __shfl_xor(a3.y, off, 64);
            t3.z = __shfl_xor(a3.z, off, 64); t3.w = __shfl_xor(a3.w, off, 64);
            a0 += t0; a1 += t1; a2 += t2; a3 += t3;
        }

        int spk = n0 + n1 + n2 + n3;
        #pragma unroll
        for (int off = 1; off < 64; off <<= 1)
            spk += __shfl_xor(spk, off, 64);
        if (lane == 0) red[wv] = spk;

        if (lane < 4) {
            const f32x4 acc = (lane == 0) ? a0 : (lane == 1) ? a1
                              : (lane == 2) ? a2 : a3;
            const f32x4 bo = ((const f32x4*)b_out)[lane];
            ((f32x4*)out)[b * 4 + lane] = 32.0f * bo + acc;
        }
    }

    __syncthreads();
    if (tid == 0) {
        int s = 0;
        #pragma unroll
        for (int i = 0; i < NW; ++i) s += red[i];
        atomicAdd(counter, s);
    }
}

// ---------------------------------------------------------------------------
// K3: spikerate = count / 2^25 (exact in fp32 since count < 2^24)
// ---------------------------------------------------------------------------
__global__ void k_fin(const int* __restrict__ counter, float* __restrict__ out)
{
    out[BDIM * ODIM] = (float)(*counter) * (1.0f / 33554432.0f);
}

// ---------------------------------------------------------------------------
extern "C" void kernel_launch(void* const* d_in, const int* in_sizes, int n_in,
                              void* d_out, int out_size, void* d_ws, size_t ws_size,
                              hipStream_t stream)
{
    const int*   x     = (const int*)  d_in[0];
    const float* emb   = (const float*)d_in[1];
    const float* W_in  = (const float*)d_in[2];
    const float* W_rec = (const float*)d_in[3];
    const float* W_out = (const float*)d_in[4];
    const float* b_out = (const float*)d_in[5];
    float* out = (float*)d_out;

    float* P       = (float*)d_ws;
    float* WT      = P + P_FLOATS;
    float* WOT     = WT + WT_FLOATS;
    int*   counter = (int*)(WOT + WOT_FLOATS);

    k_prep<<<642, 256, 0, stream>>>(emb, W_in, W_rec, W_out, P, WT, WOT, counter);
    k_main<<<BDIM / NW, 1024, 0, stream>>>(x, P, WT, WOT, b_out, out, counter);
    k_fin<<<1, 1, 0, stream>>>(counter, out);
}

// Round 10
// 62.121 us; speedup vs baseline: 7.6578x; 1.0883x over previous
//
#include <hip/hip_runtime.h>

// ---------------------------------------------------------------------------
// SNN Perceptron Equalizer (LIF recurrent net), MI355X
//
//  * ff = xt@W_in^T  ->  <=3 precomputed rows P[t][seg][sym][h] (fp64-built).
//  * One WAVE per batch element; lane l holds h=4l..4l+3 (f32x4 state).
//    16 waves / 1024-thread block, 1 block/CU. launch_bounds(1024,4) ->
//    128-VGPR cap (stops occupancy-driven regalloc from sinking prefetches).
//  * The op is BYTES-bound: ~(2.25KB P + c*1KB WT) per wave-step through the
//    ~64B/cyc CU L1 port. Split the WT gather across pipes:
//      - rows 0..151 (59%) staged in LDS (153KB); read at CONSUME time with
//        batched ds_read_b128 (LDS dummies -> LDS zero row). Parallel pipe.
//      - rows 152..255 from L2 into SIX named slots with a TWO-step window:
//        i_t = (0.8*i_{t-1} + ff_t) + rec(z_{t-1}), and i_t is first used at
//        t+1 -> gathers issued at ballot(z_t) consumed at t+2 (partial-i +
//        lazy rec add, identical rounding). Exact-c guards: no dummy L2/L1
//        traffic. Rare overflow (c_G>6) serial at consume.
//  * z_sum[b,:] = 32*b_out + sum_h cnt[b,h]*W_out[:,h]; rate = spikes/2^25.
// ---------------------------------------------------------------------------

typedef float f32x4 __attribute__((ext_vector_type(4)));

#define T_STEPS 32
#define FDIM    41
#define ODIM    16
#define BDIM    4096
#define MF      164

#define P_FLOATS   (32 * 3 * 16 * 256)
#define WT_ROWS    257                  // row 256 = zeros (safety)
#define WT_FLOATS  (WT_ROWS * 256)
#define WOT_FLOATS (256 * 16)

#define LROWS      152                  // WT rows 0..151 in LDS (l<38)
#define LBITS      38
#define LMASK      ((1ULL << LBITS) - 1)
#define GBASE      38
#define NW         16

#define HAS3(T) ((((T) * MF) & 127) > 92)

// ---------------------------------------------------------------------------
// K1: build P (fp64 accum), transpose W_rec (+zero row), W_out^T, counter=0.
// ---------------------------------------------------------------------------
__global__ __launch_bounds__(256) void k_prep(const float* __restrict__ emb,
                                              const float* __restrict__ W_in,
                                              const float* __restrict__ W_rec,
                                              const float* __restrict__ W_out,
                                              float* __restrict__ P,
                                              float* __restrict__ WT,
                                              float* __restrict__ WOT,
                                              int* __restrict__ counter)
{
    const int bid = blockIdx.x;
    const int tid = threadIdx.x;

    if (bid < 384) {
        const int g  = bid & 3;
        const int ts = bid >> 2;
        const int t  = ts / 3;
        const int si = ts % 3;
        const int k0   = t * MF;
        const int f    = (k0 >> 7) + si;
        const int base = f << 7;
        const int c0   = max(k0, base) - base;
        const int c1   = min(k0 + MF, base + 128) - base;
        const int len  = c1 - c0;

        if (len <= 0) {
            #pragma unroll
            for (int s = 0; s < 4; ++s)
                P[((t * 3 + si) * 16 + 4 * g + s) * 256 + tid] = 0.0f;
            return;
        }

        __shared__ float emb_lds[4][128];
        for (int idx = tid; idx < 4 * 128; idx += 256) {
            const int s = idx >> 7, u = idx & 127;
            if (u < len) emb_lds[s][u] = emb[((4 * g + s) << 7) + c0 + u];
        }
        __syncthreads();

        const int j0 = base + c0 - k0;
        double a0 = 0.0, a1 = 0.0, a2 = 0.0, a3 = 0.0;
        for (int u = 0; u < len; ++u) {
            const double w = (double)W_in[tid * MF + j0 + u];
            a0 += w * (double)emb_lds[0][u];
            a1 += w * (double)emb_lds[1][u];
            a2 += w * (double)emb_lds[2][u];
            a3 += w * (double)emb_lds[3][u];
        }
        P[((t * 3 + si) * 16 + 4 * g + 0) * 256 + tid] = (float)a0;
        P[((t * 3 + si) * 16 + 4 * g + 1) * 256 + tid] = (float)a1;
        P[((t * 3 + si) * 16 + 4 * g + 2) * 256 + tid] = (float)a2;
        P[((t * 3 + si) * 16 + 4 * g + 3) * 256 + tid] = (float)a3;
    } else if (bid < 641) {
        const int h = bid - 384;                // 0..256
        if (h < 256) {
            WT[h * 256 + tid] = W_rec[tid * 256 + h];
        } else {
            WT[256 * 256 + tid] = 0.0f;
            if (tid == 0) *counter = 0;
        }
    } else {
        #pragma unroll
        for (int o = 0; o < ODIM; ++o)
            WOT[tid * ODIM + o] = W_out[o * 256 + tid];
    }
}

// ---------------------------------------------------------------------------
// K2: main LIF scan. 256 blocks x 1024 threads (16 waves, wave = batch elem).
// ---------------------------------------------------------------------------
__global__ __launch_bounds__(1024, 4) void k_main(const int* __restrict__ x,
                                                  const float* __restrict__ P,
                                                  const float* __restrict__ WT,
                                                  const float* __restrict__ WOT,
                                                  const float* __restrict__ b_out,
                                                  float* __restrict__ out,
                                                  int* __restrict__ counter)
{
#pragma clang fp contract(off)
    __shared__ f32x4 WTl[(LROWS + 1) * 64];   // 153 KB; row LROWS = zeros
    __shared__ int   red[NW];

    const int tid  = threadIdx.x;
    const int lane = tid & 63;
    const int wv   = __builtin_amdgcn_readfirstlane(tid >> 6);
    const int b    = blockIdx.x * NW + wv;

    const f32x4* __restrict__ P4  = (const f32x4*)P;
    const f32x4* __restrict__ WT4 = (const f32x4*)WT;

    const f32x4 zero4 = {0.f, 0.f, 0.f, 0.f};
    for (int i = tid; i < LROWS * 64; i += 1024) WTl[i] = WT4[i];
    if (tid < 64) WTl[LROWS * 64 + tid] = zero4;
    __syncthreads();

    const int xv = (lane < FDIM) ? x[b * FDIM + lane] : 0;

    f32x4 vm = zero4, partial = zero4;
    int n0 = 0, n1 = 0, n2 = 0, n3 = 0;

    // global named slots (2 generations, parity A/B)
    f32x4 gA0 = zero4, gA1 = zero4, gA2 = zero4, gA3 = zero4, gA4 = zero4, gA5 = zero4;
    f32x4 gB0 = zero4, gB1 = zero4, gB2 = zero4, gB3 = zero4, gB4 = zero4, gB5 = zero4;
    int cgA = 0, cgB = 0;
    unsigned long long lA0 = 0, lA1 = 0, lA2 = 0, lA3 = 0;   // LDS-side masks
    unsigned long long lB0 = 0, lB1 = 0, lB2 = 0, lB3 = 0;
    unsigned long long oA0 = 0, oA1 = 0, oA2 = 0, oA3 = 0;   // G overflow masks
    unsigned long long oB0 = 0, oB1 = 0, oB2 = 0, oB3 = 0;
    f32x4 pf0 = zero4, pf1 = zero4, pf2 = zero4;

    // prologue: ff rows for t=0 (2 segments)
    pf0 = P4[(0 * 16 + __builtin_amdgcn_readlane(xv, 0)) * 64 + lane];
    pf1 = P4[(1 * 16 + __builtin_amdgcn_readlane(xv, 1)) * 64 + lane];

    #define PEEL_L(dst)                                                        \
        if (q0)      { dst = 4*(int)__builtin_ctzll(q0)+0; q0 &= q0-1; }       \
        else if (q1) { dst = 4*(int)__builtin_ctzll(q1)+1; q1 &= q1-1; }       \
        else if (q2) { dst = 4*(int)__builtin_ctzll(q2)+2; q2 &= q2-1; }       \
        else if (q3) { dst = 4*(int)__builtin_ctzll(q3)+3; q3 &= q3-1; }

    #define PEEL_G(dst)                                                        \
        if (h0)      { dst = 4*(GBASE+(int)__builtin_ctzll(h0))+0; h0 &= h0-1; } \
        else if (h1) { dst = 4*(GBASE+(int)__builtin_ctzll(h1))+1; h1 &= h1-1; } \
        else if (h2) { dst = 4*(GBASE+(int)__builtin_ctzll(h2))+2; h2 &= h2-1; } \
        else if (h3) { dst = 4*(GBASE+(int)__builtin_ctzll(h3))+3; h3 &= h3-1; }

    #define STEP(TC, CP)                                                       \
    {                                                                          \
        /* stage 1: i_full(TC-1) = partial + rec(z_{TC-2}) */                  \
        f32x4 rec = zero4;                                                     \
        {   /* LDS side: batched ds_read_b128, 4 at a time */                  \
            unsigned long long q0 = l##CP##0, q1 = l##CP##1,                   \
                               q2 = l##CP##2, q3 = l##CP##3;                   \
            int cl = __popcll(q0)+__popcll(q1)+__popcll(q2)+__popcll(q3);      \
            while (cl > 0) {                                                   \
                int w0 = LROWS, w1 = LROWS, w2 = LROWS, w3 = LROWS;            \
                PEEL_L(w0) PEEL_L(w1) PEEL_L(w2) PEEL_L(w3)                    \
                const f32x4 b0_ = WTl[w0 * 64 + lane];                         \
                const f32x4 b1_ = WTl[w1 * 64 + lane];                         \
                const f32x4 b2_ = WTl[w2 * 64 + lane];                         \
                const f32x4 b3_ = WTl[w3 * 64 + lane];                         \
                rec += ((b0_ + b1_) + (b2_ + b3_));                            \
                cl -= 4;                                                       \
            }                                                                  \
        }                                                                      \
        if (cg##CP > 0) rec += g##CP##0;                                       \
        if (cg##CP > 1) rec += g##CP##1;                                       \
        if (cg##CP > 2) rec += g##CP##2;                                       \
        if (cg##CP > 3) rec += g##CP##3;                                       \
        if (cg##CP > 4) rec += g##CP##4;                                       \
        if (cg##CP > 5) rec += g##CP##5;                                       \
        while (o##CP##0) { const int r_ = 4*(GBASE+(int)__builtin_ctzll(o##CP##0))+0; \
                           o##CP##0 &= o##CP##0-1; rec += WT4[r_*64+lane]; }   \
        while (o##CP##1) { const int r_ = 4*(GBASE+(int)__builtin_ctzll(o##CP##1))+1; \
                           o##CP##1 &= o##CP##1-1; rec += WT4[r_*64+lane]; }   \
        while (o##CP##2) { const int r_ = 4*(GBASE+(int)__builtin_ctzll(o##CP##2))+2; \
                           o##CP##2 &= o##CP##2-1; rec += WT4[r_*64+lane]; }   \
        while (o##CP##3) { const int r_ = 4*(GBASE+(int)__builtin_ctzll(o##CP##3))+3; \
                           o##CP##3 &= o##CP##3-1; rec += WT4[r_*64+lane]; }   \
        const f32x4 ifull = partial + rec;                                     \
        /* stage 2: LIF + spike decision */                                    \
        const f32x4 vdec = vm + 0.1f * (ifull - vm);                           \
        const f32x4 idec = ifull * 0.8f;                                       \
        const bool z0 = vdec.x > 1.0f, z1 = vdec.y > 1.0f,                     \
                   z2 = vdec.z > 1.0f, z3 = vdec.w > 1.0f;                     \
        const unsigned long long m0 = __ballot(z0), m1 = __ballot(z1),         \
                                 m2 = __ballot(z2), m3 = __ballot(z3);         \
        vm.x = z0 ? 0.0f : vdec.x;  vm.y = z1 ? 0.0f : vdec.y;                 \
        vm.z = z2 ? 0.0f : vdec.z;  vm.w = z3 ? 0.0f : vdec.w;                 \
        n0 += z0; n1 += z1; n2 += z2; n3 += z3;                                \
        /* stage 3: partial(TC) = idec + ff(TC); prefetch P(TC+1) */           \
        f32x4 ff = pf0 + pf1;                                                  \
        if (HAS3(TC)) ff += pf2;                                               \
        partial = idec + ff;                                                   \
        if ((TC) + 1 < T_STEPS) {                                              \
            const int f0_ = (((TC) + 1) * MF) >> 7;                            \
            pf0 = P4[(((TC)+1)*3 + 0)*16*64                                    \
                     + __builtin_amdgcn_readlane(xv, f0_) * 64 + lane];        \
            pf1 = P4[((((TC)+1)*3 + 1)*16                                      \
                     + __builtin_amdgcn_readlane(xv, f0_ + 1)) * 64 + lane];   \
            if (HAS3((TC) + 1))                                                \
                pf2 = P4[((((TC)+1)*3 + 2)*16                                  \
                         + __builtin_amdgcn_readlane(xv, f0_ + 2)) * 64 + lane]; \
        }                                                                      \
        /* stage 4: issue gathers for z_TC (consumed at TC+2) */               \
        if ((TC) + 2 < T_STEPS) {                                              \
            l##CP##0 = m0 & LMASK; l##CP##1 = m1 & LMASK;                      \
            l##CP##2 = m2 & LMASK; l##CP##3 = m3 & LMASK;                      \
            unsigned long long h0 = m0 >> LBITS, h1 = m1 >> LBITS,             \
                               h2 = m2 >> LBITS, h3 = m3 >> LBITS;             \
            const int cg_ = __popcll(h0)+__popcll(h1)+__popcll(h2)+__popcll(h3); \
            cg##CP = cg_;                                                      \
            int u_ = 256;                                                      \
            if (cg_ > 0) { PEEL_G(u_) g##CP##0 = WT4[u_ * 64 + lane];          \
            if (cg_ > 1) { PEEL_G(u_) g##CP##1 = WT4[u_ * 64 + lane];          \
            if (cg_ > 2) { PEEL_G(u_) g##CP##2 = WT4[u_ * 64 + lane];          \
            if (cg_ > 3) { PEEL_G(u_) g##CP##3 = WT4[u_ * 64 + lane];          \
            if (cg_ > 4) { PEEL_G(u_) g##CP##4 = WT4[u_ * 64 + lane];          \
            if (cg_ > 5) { PEEL_G(u_) g##CP##5 = WT4[u_ * 64 + lane]; }}}}}}   \
            o##CP##0 = h0; o##CP##1 = h1; o##CP##2 = h2; o##CP##3 = h3;        \
        } else {                                                               \
            cg##CP = 0;                                                        \
            l##CP##0 = l##CP##1 = l##CP##2 = l##CP##3 = 0;                     \
            o##CP##0 = o##CP##1 = o##CP##2 = o##CP##3 = 0;                     \
        }                                                                      \
    }

    #pragma unroll
    for (int tt = 0; tt < T_STEPS; tt += 2) {
        STEP(tt, A)
        STEP(tt + 1, B)
    }
    #undef STEP
    #undef PEEL_L
    #undef PEEL_G

    // --- epilogue: z_sum[b,o] = 32*b_out[o] + sum_h cnt[h]*W_out[o,h] ---
    {
        const f32x4* __restrict__ WOT4 = (const f32x4*)WOT; // [256][4] f32x4
        const float fn0 = (float)n0, fn1 = (float)n1,
                    fn2 = (float)n2, fn3 = (float)n3;
        const int r0 = 4 * lane * 4;
        f32x4 a0 = fn0 * WOT4[r0 + 0]  + fn1 * WOT4[r0 + 4]
                 + fn2 * WOT4[r0 + 8]  + fn3 * WOT4[r0 + 12];
        f32x4 a1 = fn0 * WOT4[r0 + 1]  + fn1 * WOT4[r0 + 5]
                 + fn2 * WOT4[r0 + 9]  + fn3 * WOT4[r0 + 13];
        f32x4 a2 = fn0 * WOT4[r0 + 2]  + fn1 * WOT4[r0 + 6]
                 + fn2 * WOT4[r0 + 10] + fn3 * WOT4[r0 + 14];
        f32x4 a3 = fn0 * WOT4[r0 + 3]  + fn1 * WOT4[r0 + 7]
                 + fn2 * WOT4[r0 + 11] + fn3 * WOT4[r0 + 15];

        #pragma unroll
        for (int off = 1; off < 64; off <<= 1) {
            f32x4 t0, t1, t2, t3;
            t0.x = __shfl_xor(a0.x, off, 64); t0.y = __shfl_xor(a0.y, off, 64);
            t0.z = __shfl_xor(a0.z, off, 64); t0.w = __shfl_xor(a0.w, off, 64);
            t1.x = __shfl_xor(a1.x, off, 64); t1.y = __shfl_xor(a1.y, off, 64);
            t1.z = __shfl_xor(a1.z, off, 64); t1.w = __shfl_xor(a1.w, off, 64);
            t2.x = __shfl_xor(a2.x, off, 64); t2.y = __shfl_xor(a2.y, off, 64);
            t2.z = __shfl_xor(a2.z, off, 64); t2.w = __shfl_xor(a2.w, off, 64);
            t3.x = __shfl_xor(a3.x, off, 64); t3.y = __shfl_xor(a3.y, off, 64);
            t3.z = __shfl_xor(a3.z, off, 64); t3.w = __shfl_xor(a3.w, off, 64);
            a0 += t0; a1 += t1; a2 += t2; a3 += t3;
        }

        int spk = n0 + n1 + n2 + n3;
        #pragma unroll
        for (int off = 1; off < 64; off <<= 1)
            spk += __shfl_xor(spk, off, 64);
        if (lane == 0) red[wv] = spk;

        if (lane < 4) {
            const f32x4 acc = (lane == 0) ? a0 : (lane == 1) ? a1
                              : (lane == 2) ? a2 : a3;
            const f32x4 bo = ((const f32x4*)b_out)[lane];
            ((f32x4*)out)[b * 4 + lane] = 32.0f * bo + acc;
        }
    }

    __syncthreads();
    if (tid == 0) {
        int s = 0;
        #pragma unroll
        for (int i = 0; i < NW; ++i) s += red[i];
        atomicAdd(counter, s);
    }
}

// ---------------------------------------------------------------------------
// K3: spikerate = count / 2^25 (exact in fp32 since count < 2^24)
// ---------------------------------------------------------------------------
__global__ void k_fin(const int* __restrict__ counter, float* __restrict__ out)
{
    out[BDIM * ODIM] = (float)(*counter) * (1.0f / 33554432.0f);
}

// ---------------------------------------------------------------------------
extern "C" void kernel_launch(void* const* d_in, const int* in_sizes, int n_in,
                              void* d_out, int out_size, void* d_ws, size_t ws_size,
                              hipStream_t stream)
{
    const int*   x     = (const int*)  d_in[0];
    const float* emb   = (const float*)d_in[1];
    const float* W_in  = (const float*)d_in[2];
    const float* W_rec = (const float*)d_in[3];
    const float* W_out = (const float*)d_in[4];
    const float* b_out = (const float*)d_in[5];
    float* out = (float*)d_out;

    float* P       = (float*)d_ws;
    float* WT      = P + P_FLOATS;
    float* WOT     = WT + WT_FLOATS;
    int*   counter = (int*)(WOT + WOT_FLOATS);

    k_prep<<<642, 256, 0, stream>>>(emb, W_in, W_rec, W_out, P, WT, WOT, counter);
    k_main<<<BDIM / NW, 1024, 0, stream>>>(x, P, WT, WOT, b_out, out, counter);
    k_fin<<<1, 1, 0, stream>>>(counter, out);
}